// Round 6
// baseline (156.676 us; speedup 1.0000x reference)
//
#include <hip/hip_runtime.h>
#include <cstdint>

#define DEVFN __device__ __forceinline__

typedef __bf16 bf16x8 __attribute__((ext_vector_type(8)));
typedef float f32x4 __attribute__((ext_vector_type(4)));
typedef unsigned int uint;

constexpr int Bc = 8, Sc = 2048, Ec = 512, Hc = 8, HDc = 64, NI = 64;
constexpr int Mtot = Bc * Sc;  // 16384
constexpr int Kdim = Ec;       // 512
constexpr int MAXITEMS = 128;  // sum ceil(n_g/32) <= 64 + 2048/32 = 128

DEVFN unsigned short f2bf(float f) {
  unsigned u = __builtin_bit_cast(unsigned, f);
  u += 0x7fffu + ((u >> 16) & 1u);  // RNE (inputs finite)
  return (unsigned short)(u >> 16);
}

typedef const void __attribute__((address_space(1))) gvoid_t;
typedef void __attribute__((address_space(3))) lvoid_t;
DEVFN void gload16(const void* g, void* l) {
  __builtin_amdgcn_global_load_lds((gvoid_t*)g, (lvoid_t*)l, 16, 0, 0);
}

DEVFN uint cvtpk(float lo, float hi) {
  uint r;
  asm("v_cvt_pk_bf16_f32 %0, %1, %2" : "=v"(r) : "v"(lo), "v"(hi));
  return r;
}

// ---------------- conversions ----------------
__global__ void cvt_x_kernel(const float* __restrict__ x, ushort* __restrict__ xb) {
  int i = blockIdx.x * 256 + threadIdx.x;  // group of 4 floats; grid exact
  float4 v = ((const float4*)x)[i];
  ushort4 o = {f2bf(v.x), f2bf(v.y), f2bf(v.z), f2bf(v.w)};
  ((ushort4*)xb)[i] = o;
}

__global__ void cvt_w_kernel(const float* __restrict__ Wq, const float* __restrict__ Wk,
                             const float* __restrict__ Wv, const float* __restrict__ Wo,
                             ushort* __restrict__ Wcat, ushort* __restrict__ Wob) {
  int i = blockIdx.x * 256 + threadIdx.x;
  int idx = i * 4;
  int n = idx >> 9, k = idx & 511;
  const float* src;
  ushort* dst;
  if (n < 512)       { src = Wq + (size_t)n * 512 + k;          dst = Wcat + (size_t)n * 512 + k; }
  else if (n < 1024) { src = Wk + (size_t)(n - 512) * 512 + k;  dst = Wcat + (size_t)n * 512 + k; }
  else if (n < 1536) { src = Wv + (size_t)(n - 1024) * 512 + k; dst = Wcat + (size_t)n * 512 + k; }
  else               { src = Wo + (size_t)(n - 1536) * 512 + k; dst = Wob + (size_t)(n - 1536) * 512 + k; }
  float4 v = *(const float4*)src;
  ushort4 o = {f2bf(v.x), f2bf(v.y), f2bf(v.z), f2bf(v.w)};
  *(ushort4*)dst = o;
}

// ---------------- deterministic counting sort by industry + work items ----------------
__global__ void sort_kernel(const int* __restrict__ ids, int* __restrict__ perm,
                            int* __restrict__ invperm, int* __restrict__ gstart,
                            int* __restrict__ gsz, int* __restrict__ items,
                            int* __restrict__ nitems) {
  __shared__ int sid[Sc];
  __shared__ int hist[NI];
  __shared__ int base[NI];
  int t = threadIdx.x;  // 256 threads, 1 block
  if (t < NI) hist[t] = 0;
  for (int i = t; i < Sc; i += 256) sid[i] = ids[i];
  __syncthreads();
  for (int i = t; i < Sc; i += 256) atomicAdd(&hist[sid[i]], 1);
  __syncthreads();
  if (t == 0) {
    int run = 0;
    for (int g = 0; g < NI; ++g) { base[g] = run; run += hist[g]; }
    // balanced work items: (group, q0) chunks of 32 queries
    int cnt = 0;
    for (int g = 0; g < NI; ++g)
      for (int q0 = 0; q0 < hist[g]; q0 += 32) items[cnt++] = (g << 16) | q0;
    *nitems = cnt;
  }
  __syncthreads();
  if (t < NI) { gstart[t] = base[t]; gsz[t] = hist[t]; }
  int lane = t & 63, w = t >> 6;
  for (int g = w; g < NI; g += 4) {  // each wave owns industries w, w+4, ...
    int run = base[g];
    for (int c = 0; c < Sc; c += 64) {
      int tok = c + lane;
      int id = sid[tok];
      unsigned long long mask = __ballot(id == g);
      if (id == g) {
        int rank = __popcll(mask & ((1ull << lane) - 1ull));
        int pos = run + rank;
        perm[pos] = tok;
        invperm[tok] = pos;
      }
      run += __popcll(mask);
    }
  }
}

// ---------------- 128x128 bf16 MFMA GEMM, 2-phase double-buffered staging --------
// C[m][n] = sum_k A[m][k]*Bw[n][k] + bias. Per K-step: issue next-tile
// global_load_lds FIRST, compute current from the other LDS buffer, then ONE
// __syncthreads() (its vmcnt(0)+lgkmcnt(0) drain lands after compute -> load
// latency overlaps MFMA). Buffer read at iter t is overwritten at t+1; the
// end-of-t barrier (all ds_reads drained) makes that safe.
template <int NTOT, bool QKV>
__global__ __launch_bounds__(256) void gemm_bt(
    const ushort* __restrict__ A, const ushort* __restrict__ Bw,
    const float* __restrict__ bias0, const float* __restrict__ bias1,
    const float* __restrict__ bias2, const int* __restrict__ invperm,
    ushort* __restrict__ qkvout, float* __restrict__ out) {
  __shared__ __align__(16) ushort sA[2][128 * 64];
  __shared__ __align__(16) ushort sB[2][128 * 64];
  const int tid = threadIdx.x;
  const int lane = tid & 63;
  const int wave = tid >> 6;
  const int wr = wave >> 1, wc = wave & 1;
  const int mbase = blockIdx.x * 128;
  const int nbase = blockIdx.y * 128;

  f32x4 acc[4][4] = {};

  const int rowS = wave * 32 + (lane >> 3);  // staging row (+ c*8)
  const int kc = lane & 7;                   // staging 16B chunk within row

  auto stage = [&](int buf, int kt) {
    const int k0 = kt * 64;
#pragma unroll
    for (int c = 0; c < 4; ++c) {
      int row = rowS + c * 8;
      int kcp = (kc ^ (row & 7)) * 8;  // pre-swizzled source -> linear LDS dest == swizzled layout
      gload16(A + (size_t)(mbase + row) * Kdim + k0 + kcp, &sA[buf][(wave * 256 + c * 64) * 8]);
      gload16(Bw + (size_t)(nbase + row) * Kdim + k0 + kcp, &sB[buf][(wave * 256 + c * 64) * 8]);
    }
  };

  stage(0, 0);
  __syncthreads();  // drain prologue staging (vmcnt(0)) before first compute

  for (int kt = 0; kt < Kdim / 64; ++kt) {
    const int cur = kt & 1;
    if (kt + 1 < Kdim / 64) stage(cur ^ 1, kt + 1);  // overlap with compute below
#pragma unroll
    for (int kk = 0; kk < 2; ++kk) {
      bf16x8 af[4], bfv[4];
#pragma unroll
      for (int i = 0; i < 4; ++i) {
        int row = wr * 64 + i * 16 + (lane & 15);
        int off = row * 128 + kk * 64 + (lane >> 4) * 16;
        off ^= (row & 7) << 4;
        af[i] = *(const bf16x8*)((const char*)sA[cur] + off);
      }
#pragma unroll
      for (int j = 0; j < 4; ++j) {
        int col = wc * 64 + j * 16 + (lane & 15);
        int off = col * 128 + kk * 64 + (lane >> 4) * 16;
        off ^= (col & 7) << 4;
        bfv[j] = *(const bf16x8*)((const char*)sB[cur] + off);
      }
#pragma unroll
      for (int i = 0; i < 4; ++i)
#pragma unroll
        for (int j = 0; j < 4; ++j)
          acc[i][j] = __builtin_amdgcn_mfma_f32_16x16x32_bf16(af[i], bfv[j], acc[i][j], 0, 0, 0);
    }
    __syncthreads();  // single barrier/iter: next buffer ready + read-safety
  }

#pragma unroll
  for (int i = 0; i < 4; ++i) {
#pragma unroll
    for (int r = 0; r < 4; ++r) {
      int m = mbase + wr * 64 + i * 16 + (lane >> 4) * 4 + r;  // C/D: row=(lane>>4)*4+reg
      if constexpr (QKV) {
        int bidx = m >> 11, s = m & (Sc - 1);
        int p = invperm[s];
#pragma unroll
        for (int j = 0; j < 4; ++j) {
          int n = nbase + wc * 64 + j * 16 + (lane & 15);  // C/D: col=lane&15
          float bv = (n < 512) ? bias0[n] : (n < 1024) ? bias1[n - 512] : bias2[n - 1024];
          float val = acc[i][j][r] + bv;
          int proj = n >> 9, h = (n >> 6) & 7, d = n & 63;
          size_t off = (size_t)proj * ((size_t)Bc * Hc * Sc * HDc) +
                       (((size_t)(bidx * Hc + h) * Sc + p) * HDc + d);
          qkvout[off] = f2bf(val);
        }
      } else {
#pragma unroll
        for (int j = 0; j < 4; ++j) {
          int n = nbase + wc * 64 + j * 16 + (lane & 15);
          out[(size_t)m * NTOT + n] = acc[i][j][r] + bias0[n];
        }
      }
    }
  }
}

// ---------------- MFMA attention: 1 wave = (bh, 32-query chunk of one group) -------
// S^T = K·Q^T (16x16x32 mfma): lane(ql,lg) holds S[k=4lg+r][q=ql] for two k-tiles.
// exp w/o max subtraction (validated round 2). P redistribution to PV B-operand via
// 8 ds_bpermute: dest (ql,lg,w) needs k-pair 8lg+2w -> tile = lg>>1 (DEST's lg),
// source lane = ql + 16*(2(lg&1)+(w>>1)), word (w&1 ? b : a).
// V^T A-fragments via reg-staged LDS transpose (full 32x64 tile coverage).
__global__ __launch_bounds__(64) void attn5_kernel(
    const ushort* __restrict__ qkv, const int* __restrict__ perm,
    const int* __restrict__ gstart, const int* __restrict__ gsz,
    const int* __restrict__ items, const int* __restrict__ nitems,
    ushort* __restrict__ obuf) {
  __shared__ __align__(16) ushort vt[64 * 40];  // Vt[d][k], rows padded to 40 ushorts (80B)
  if ((int)blockIdx.x >= *nitems) return;
  const int iv = items[blockIdx.x];
  const int g = iv >> 16, q0 = iv & 0xffff;
  const int bh = blockIdx.y;
  const int start = gstart[g], n = gsz[g];
  const int lane = threadIdx.x;
  const int ql = lane & 15, lg = lane >> 4;

  const size_t planeSz = (size_t)Bc * Hc * Sc * HDc;
  const ushort* qb = qkv + (size_t)bh * Sc * HDc;
  const ushort* kb = qb + planeSz;
  const ushort* vb = kb + planeSz;

  // Q fragments (B-operand): lane holds col q=ql, kdim d = h*32 + lg*8 + (0..7)
  bf16x8 qf[2][2];
#pragma unroll
  for (int qt = 0; qt < 2; ++qt) {
    int row = min(start + q0 + qt * 16 + ql, Sc - 1);
#pragma unroll
    for (int h = 0; h < 2; ++h)
      qf[qt][h] = *(const bf16x8*)(qb + (size_t)row * HDc + h * 32 + lg * 8);
  }

  f32x4 oacc[2][4] = {};  // [qt][dq]: O^T tile, lane holds col q=ql, row d=dq*16+4lg+r
  float lsum[2] = {0.f, 0.f};

  const int vk = lane & 31;          // V staging: row k within 32-tile
  const int vh = (lane >> 5) * 32;   // V staging: d half [vh, vh+32)
  const int Lbase = 4 * (ql + 32 * (lg & 1));  // bpermute source byte addr

  const int npair = (n + 31) >> 5;
  for (int pr = 0; pr < npair; ++pr) {
    const int c0 = pr * 32;
    // issue V global loads early (latency hides under QK + softmax)
    int vrow = min(start + c0 + vk, Sc - 1);
    const uint4* vp = (const uint4*)(vb + (size_t)vrow * HDc + vh);
    uint4 v0 = vp[0], v1 = vp[1], v2 = vp[2], v3 = vp[3];

    // K fragments (A-operand): lane holds row k=ql (in tile), kdim d = h*32+lg*8
    bf16x8 kf[2][2];
#pragma unroll
    for (int t = 0; t < 2; ++t) {
      int row = min(start + c0 + t * 16 + ql, Sc - 1);
#pragma unroll
      for (int h = 0; h < 2; ++h)
        kf[t][h] = *(const bf16x8*)(kb + (size_t)row * HDc + h * 32 + lg * 8);
    }

    uint pw[2][4];
#pragma unroll
    for (int qt = 0; qt < 2; ++qt) {
      f32x4 s0 = {}, s1 = {};
      s0 = __builtin_amdgcn_mfma_f32_16x16x32_bf16(kf[0][0], qf[qt][0], s0, 0, 0, 0);
      s0 = __builtin_amdgcn_mfma_f32_16x16x32_bf16(kf[0][1], qf[qt][1], s0, 0, 0, 0);
      s1 = __builtin_amdgcn_mfma_f32_16x16x32_bf16(kf[1][0], qf[qt][0], s1, 0, 0, 0);
      s1 = __builtin_amdgcn_mfma_f32_16x16x32_bf16(kf[1][1], qf[qt][1], s1, 0, 0, 0);
      float p0[4], p1[4];
      float ls = 0.f;
#pragma unroll
      for (int r = 0; r < 4; ++r) {
        int kk = c0 + 4 * lg + r;
        float e0 = (kk < n) ? __expf(s0[r] * 0.125f) : 0.f;
        float e1 = (kk + 16 < n) ? __expf(s1[r] * 0.125f) : 0.f;
        p0[r] = e0;
        p1[r] = e1;
        ls += e0 + e1;
      }
      lsum[qt] += ls;
      uint a0 = cvtpk(p0[0], p0[1]), b0 = cvtpk(p0[2], p0[3]);
      uint a1 = cvtpk(p1[0], p1[1]), b1 = cvtpk(p1[2], p1[3]);
      // 8 bpermutes: tile chosen by DEST lg>>1 after the pull
      uint pA0 = __builtin_amdgcn_ds_bpermute(Lbase, a0);
      uint pB0 = __builtin_amdgcn_ds_bpermute(Lbase, b0);
      uint pA1 = __builtin_amdgcn_ds_bpermute(Lbase, a1);
      uint pB1 = __builtin_amdgcn_ds_bpermute(Lbase, b1);
      uint pC0 = __builtin_amdgcn_ds_bpermute(Lbase + 64, a0);
      uint pD0 = __builtin_amdgcn_ds_bpermute(Lbase + 64, b0);
      uint pC1 = __builtin_amdgcn_ds_bpermute(Lbase + 64, a1);
      uint pD1 = __builtin_amdgcn_ds_bpermute(Lbase + 64, b1);
      bool t0 = lg < 2;
      pw[qt][0] = t0 ? pA0 : pA1;
      pw[qt][1] = t0 ? pB0 : pB1;
      pw[qt][2] = t0 ? pC0 : pC1;
      pw[qt][3] = t0 ? pD0 : pD1;
    }

    // LDS transpose of V tile: Vt[d][k] <- V[k][d]; full coverage: 32 writes/lane
    {
      uint w[16] = {v0.x, v0.y, v0.z, v0.w, v1.x, v1.y, v1.z, v1.w,
                    v2.x, v2.y, v2.z, v2.w, v3.x, v3.y, v3.z, v3.w};
#pragma unroll
      for (int i = 0; i < 16; ++i) {
        vt[(vh + 2 * i) * 40 + vk] = (ushort)(w[i] & 0xffffu);
        vt[(vh + 2 * i + 1) * 40 + vk] = (ushort)(w[i] >> 16);
      }
    }
    asm volatile("s_waitcnt lgkmcnt(0)" ::: "memory");  // cross-lane write->read (1 wave)
    __builtin_amdgcn_sched_barrier(0);
    bf16x8 vf[4];
#pragma unroll
    for (int dq = 0; dq < 4; ++dq)
      vf[dq] = *(const bf16x8*)(vt + (dq * 16 + ql) * 40 + lg * 8);
    asm volatile("s_waitcnt lgkmcnt(0)" ::: "memory");  // reads done before next-iter writes
    __builtin_amdgcn_sched_barrier(0);
#pragma unroll
    for (int qt = 0; qt < 2; ++qt) {
      union { uint u[4]; bf16x8 v; } pf;
      pf.u[0] = pw[qt][0]; pf.u[1] = pw[qt][1]; pf.u[2] = pw[qt][2]; pf.u[3] = pw[qt][3];
#pragma unroll
      for (int dq = 0; dq < 4; ++dq)
        oacc[qt][dq] = __builtin_amdgcn_mfma_f32_16x16x32_bf16(vf[dq], pf.v, oacc[qt][dq], 0, 0, 0);
    }
  }

  // epilogue: reduce denominator across lane groups, scale, store O^T columns
#pragma unroll
  for (int qt = 0; qt < 2; ++qt) {
    float l = lsum[qt];
    l += __shfl_xor(l, 16);
    l += __shfl_xor(l, 32);
    float inv = 1.f / l;
    int qi = q0 + qt * 16 + ql;
    int sorig = perm[min(start + qi, Sc - 1)];
    if (qi < n) {
      ushort* op = obuf + (size_t)((bh >> 3) * Sc + sorig) * Ec + (bh & 7) * HDc + lg * 4;
#pragma unroll
      for (int dq = 0; dq < 4; ++dq) {
        uint w0 = cvtpk(oacc[qt][dq][0] * inv, oacc[qt][dq][1] * inv);
        uint w1 = cvtpk(oacc[qt][dq][2] * inv, oacc[qt][dq][3] * inv);
        uint2 wv = {w0, w1};
        *(uint2*)(op + dq * 16) = wv;
      }
    }
  }
}

extern "C" void kernel_launch(void* const* d_in, const int* in_sizes, int n_in,
                              void* d_out, int out_size, void* d_ws, size_t ws_size,
                              hipStream_t stream) {
  const float* x  = (const float*)d_in[0];
  const float* Wq = (const float*)d_in[1];
  const float* bq = (const float*)d_in[2];
  const float* Wk = (const float*)d_in[3];
  const float* bk = (const float*)d_in[4];
  const float* Wv = (const float*)d_in[5];
  const float* bv = (const float*)d_in[6];
  const float* Wo = (const float*)d_in[7];
  const float* bo = (const float*)d_in[8];
  const int* ids  = (const int*)d_in[9];
  float* out = (float*)d_out;

  char* ws = (char*)d_ws;
  // layout (bytes): xb 16M | Wcat 1.5M | Wob 0.5M | qkv 48M | obuf 16M | ints
  ushort* xb   = (ushort*)(ws);
  ushort* Wcat = (ushort*)(ws + 16777216);
  ushort* Wob  = (ushort*)(ws + 18350080);
  ushort* qkv  = (ushort*)(ws + 18874368);
  ushort* obuf = (ushort*)(ws + 69206016);
  int* perm    = (int*)(ws + 85983232);
  int* invperm = perm + Sc;
  int* gstart  = invperm + Sc;
  int* gsz     = gstart + NI;
  int* items   = gsz + NI;
  int* nitems  = items + MAXITEMS;

  cvt_x_kernel<<<dim3(Mtot * Ec / 4 / 256), dim3(256), 0, stream>>>(x, xb);
  cvt_w_kernel<<<dim3(2048 * 512 / 4 / 256), dim3(256), 0, stream>>>(Wq, Wk, Wv, Wo, Wcat, Wob);
  sort_kernel<<<dim3(1), dim3(256), 0, stream>>>(ids, perm, invperm, gstart, gsz, items, nitems);
  gemm_bt<1536, true><<<dim3(Mtot / 128, 1536 / 128), dim3(256), 0, stream>>>(
      xb, Wcat, bq, bk, bv, invperm, qkv, (float*)nullptr);
  attn5_kernel<<<dim3(MAXITEMS, Bc * Hc), dim3(64), 0, stream>>>(qkv, perm, gstart, gsz, items,
                                                                 nitems, obuf);
  gemm_bt<512, false><<<dim3(Mtot / 128, 512 / 128), dim3(256), 0, stream>>>(
      obuf, Wob, bo, bo, bo, invperm, (ushort*)nullptr, out);
}

// Round 7
// 154.573 us; speedup vs baseline: 1.0136x; 1.0136x over previous
//
#include <hip/hip_runtime.h>
#include <cstdint>

#define DEVFN __device__ __forceinline__

typedef __bf16 bf16x8 __attribute__((ext_vector_type(8)));
typedef float f32x4 __attribute__((ext_vector_type(4)));
typedef unsigned int uint;

constexpr int Bc = 8, Sc = 2048, Ec = 512, Hc = 8, HDc = 64, NI = 64;
constexpr int Mtot = Bc * Sc;  // 16384
constexpr int Kdim = Ec;       // 512
constexpr int MAXITEMS = 128;  // sum ceil(n_g/32) <= 64 + 2048/32 = 128

DEVFN unsigned short f2bf(float f) {
  unsigned u = __builtin_bit_cast(unsigned, f);
  u += 0x7fffu + ((u >> 16) & 1u);  // RNE (inputs finite)
  return (unsigned short)(u >> 16);
}

typedef const void __attribute__((address_space(1))) gvoid_t;
typedef void __attribute__((address_space(3))) lvoid_t;
DEVFN void gload16(const void* g, void* l) {
  __builtin_amdgcn_global_load_lds((gvoid_t*)g, (lvoid_t*)l, 16, 0, 0);
}

DEVFN uint cvtpk(float lo, float hi) {
  uint r;
  asm("v_cvt_pk_bf16_f32 %0, %1, %2" : "=v"(r) : "v"(lo), "v"(hi));
  return r;
}

// ---------------- conversions ----------------
// cvt_x permutes tokens into SORTED space: xb[b][p][:] = bf16(x[b][perm[p]][:]).
// Downstream (QKV epilogue, attn) then runs entirely in sorted space -> all its
// writes are contiguous; only the out-proj epilogue scatters rows back via perm.
__global__ void cvt_x_kernel(const float* __restrict__ x, const int* __restrict__ perm,
                             ushort* __restrict__ xb) {
  int i = blockIdx.x * 256 + threadIdx.x;  // 4-float chunk; grid exact
  int mp = i >> 7;                         // row in sorted space (128 chunks/row)
  int c = i & 127;
  int b = mp >> 11, p = mp & (Sc - 1);
  int srow = (b << 11) | perm[p];
  float4 v = *(const float4*)(x + (size_t)srow * Ec + c * 4);
  ushort4 o = {f2bf(v.x), f2bf(v.y), f2bf(v.z), f2bf(v.w)};
  ((ushort4*)xb)[i] = o;
}

__global__ void cvt_w_kernel(const float* __restrict__ Wq, const float* __restrict__ Wk,
                             const float* __restrict__ Wv, const float* __restrict__ Wo,
                             ushort* __restrict__ Wcat, ushort* __restrict__ Wob) {
  int i = blockIdx.x * 256 + threadIdx.x;
  int idx = i * 4;
  int n = idx >> 9, k = idx & 511;
  const float* src;
  ushort* dst;
  if (n < 512)       { src = Wq + (size_t)n * 512 + k;          dst = Wcat + (size_t)n * 512 + k; }
  else if (n < 1024) { src = Wk + (size_t)(n - 512) * 512 + k;  dst = Wcat + (size_t)n * 512 + k; }
  else if (n < 1536) { src = Wv + (size_t)(n - 1024) * 512 + k; dst = Wcat + (size_t)n * 512 + k; }
  else               { src = Wo + (size_t)(n - 1536) * 512 + k; dst = Wob + (size_t)(n - 1536) * 512 + k; }
  float4 v = *(const float4*)src;
  ushort4 o = {f2bf(v.x), f2bf(v.y), f2bf(v.z), f2bf(v.w)};
  *(ushort4*)dst = o;
}

// ---------------- deterministic counting sort by industry + work items ----------------
__global__ void sort_kernel(const int* __restrict__ ids, int* __restrict__ perm,
                            int* __restrict__ gstart, int* __restrict__ gsz,
                            int* __restrict__ items, int* __restrict__ nitems) {
  __shared__ int sid[Sc];
  __shared__ int hist[NI];
  __shared__ int base[NI];
  int t = threadIdx.x;  // 256 threads, 1 block
  if (t < NI) hist[t] = 0;
  for (int i = t; i < Sc; i += 256) sid[i] = ids[i];
  __syncthreads();
  for (int i = t; i < Sc; i += 256) atomicAdd(&hist[sid[i]], 1);
  __syncthreads();
  if (t == 0) {
    int run = 0;
    for (int g = 0; g < NI; ++g) { base[g] = run; run += hist[g]; }
    // balanced work items: (group, q0) chunks of 32 queries
    int cnt = 0;
    for (int g = 0; g < NI; ++g)
      for (int q0 = 0; q0 < hist[g]; q0 += 32) items[cnt++] = (g << 16) | q0;
    *nitems = cnt;
  }
  __syncthreads();
  if (t < NI) { gstart[t] = base[t]; gsz[t] = hist[t]; }
  int lane = t & 63, w = t >> 6;
  for (int g = w; g < NI; g += 4) {  // each wave owns industries w, w+4, ...
    int run = base[g];
    for (int c = 0; c < Sc; c += 64) {
      int tok = c + lane;
      int id = sid[tok];
      unsigned long long mask = __ballot(id == g);
      if (id == g) {
        int rank = __popcll(mask & ((1ull << lane) - 1ull));
        perm[run + rank] = tok;
      }
      run += __popcll(mask);
    }
  }
}

// ---------------- 128x128 bf16 MFMA GEMM, 2-phase dbuf + XCD-locality swizzle ----
// XCD x owns contiguous M rows [x*2048,(x+1)*2048) (A-slice 2MB fits 4MB L2);
// panels iterate panel-major within the XCD -> A fetched from L3 once, re-reads
// are L2 hits. Requires 1-D grid, nwg % 8 == 0 (1536 / 512: ok), M/128 == 128.
// QKV=true: everything in sorted space -> qkv rows written contiguously at p=m.
// QKV=false: out rows scattered back to original tokens via permarg.
template <int NTOT, bool QKV>
__global__ __launch_bounds__(256) void gemm_bt(
    const ushort* __restrict__ A, const ushort* __restrict__ Bw,
    const float* __restrict__ bias0, const float* __restrict__ bias1,
    const float* __restrict__ bias2, const int* __restrict__ permarg,
    ushort* __restrict__ qkvout, float* __restrict__ out) {
  __shared__ __align__(16) ushort sA[2][128 * 64];
  __shared__ __align__(16) ushort sB[2][128 * 64];
  const int tid = threadIdx.x;
  const int lane = tid & 63;
  const int wave = tid >> 6;
  const int wr = wave >> 1, wc = wave & 1;
  // XCD-locality swizzle (consecutive blockIdx round-robin across 8 XCDs)
  const int orig = blockIdx.x;
  const int xcd = orig & 7, gl = orig >> 3;
  const int mbase = (xcd * 16 + (gl & 15)) * 128;
  const int nbase = (gl >> 4) * 128;

  f32x4 acc[4][4] = {};

  const int rowS = wave * 32 + (lane >> 3);  // staging row (+ c*8)
  const int kc = lane & 7;                   // staging 16B chunk within row

  auto stage = [&](int buf, int kt) {
    const int k0 = kt * 64;
#pragma unroll
    for (int c = 0; c < 4; ++c) {
      int row = rowS + c * 8;
      int kcp = (kc ^ (row & 7)) * 8;  // pre-swizzled source -> linear LDS dest == swizzled layout
      gload16(A + (size_t)(mbase + row) * Kdim + k0 + kcp, &sA[buf][(wave * 256 + c * 64) * 8]);
      gload16(Bw + (size_t)(nbase + row) * Kdim + k0 + kcp, &sB[buf][(wave * 256 + c * 64) * 8]);
    }
  };

  stage(0, 0);
  __syncthreads();  // drain prologue staging (vmcnt(0)) before first compute

  for (int kt = 0; kt < Kdim / 64; ++kt) {
    const int cur = kt & 1;
    if (kt + 1 < Kdim / 64) stage(cur ^ 1, kt + 1);  // overlap with compute below
#pragma unroll
    for (int kk = 0; kk < 2; ++kk) {
      bf16x8 af[4], bfv[4];
#pragma unroll
      for (int i = 0; i < 4; ++i) {
        int row = wr * 64 + i * 16 + (lane & 15);
        int off = row * 128 + kk * 64 + (lane >> 4) * 16;
        off ^= (row & 7) << 4;
        af[i] = *(const bf16x8*)((const char*)sA[cur] + off);
      }
#pragma unroll
      for (int j = 0; j < 4; ++j) {
        int col = wc * 64 + j * 16 + (lane & 15);
        int off = col * 128 + kk * 64 + (lane >> 4) * 16;
        off ^= (col & 7) << 4;
        bfv[j] = *(const bf16x8*)((const char*)sB[cur] + off);
      }
#pragma unroll
      for (int i = 0; i < 4; ++i)
#pragma unroll
        for (int j = 0; j < 4; ++j)
          acc[i][j] = __builtin_amdgcn_mfma_f32_16x16x32_bf16(af[i], bfv[j], acc[i][j], 0, 0, 0);
    }
    __syncthreads();  // single barrier/iter: next buffer ready + read-safety
  }

#pragma unroll
  for (int i = 0; i < 4; ++i) {
#pragma unroll
    for (int r = 0; r < 4; ++r) {
      int m = mbase + wr * 64 + i * 16 + (lane >> 4) * 4 + r;  // C/D: row=(lane>>4)*4+reg
      int bidx = m >> 11, p = m & (Sc - 1);
      if constexpr (QKV) {
#pragma unroll
        for (int j = 0; j < 4; ++j) {
          int n = nbase + wc * 64 + j * 16 + (lane & 15);  // C/D: col=lane&15
          float bv = (n < 512) ? bias0[n] : (n < 1024) ? bias1[n - 512] : bias2[n - 1024];
          float val = acc[i][j][r] + bv;
          int proj = n >> 9, h = (n >> 6) & 7, d = n & 63;
          size_t off = (size_t)proj * ((size_t)Bc * Hc * Sc * HDc) +
                       (((size_t)(bidx * Hc + h) * Sc + p) * HDc + d);
          qkvout[off] = f2bf(val);  // contiguous rows: p == m (sorted space)
        }
      } else {
        int orow = (bidx << 11) | permarg[p];  // scatter back to token order
#pragma unroll
        for (int j = 0; j < 4; ++j) {
          int n = nbase + wc * 64 + j * 16 + (lane & 15);
          out[(size_t)orow * NTOT + n] = acc[i][j][r] + bias0[n];
        }
      }
    }
  }
}

// ---------------- MFMA attention: 1 wave = (bh, 32-query chunk of one group) -------
// All in sorted space (qkv sorted; obuf sorted). S^T = K·Q^T; exp w/o max
// subtraction (validated). P redistribution via 8 ds_bpermute + dest-side select.
// V^T A-fragments via reg-staged LDS transpose (full 32x64 coverage).
__global__ __launch_bounds__(64) void attn5_kernel(
    const ushort* __restrict__ qkv, const int* __restrict__ gstart,
    const int* __restrict__ gsz, const int* __restrict__ items,
    const int* __restrict__ nitems, ushort* __restrict__ obuf) {
  __shared__ __align__(16) ushort vt[64 * 40];  // Vt[d][k], rows padded to 40 ushorts (80B)
  if ((int)blockIdx.x >= *nitems) return;
  const int iv = items[blockIdx.x];
  const int g = iv >> 16, q0 = iv & 0xffff;
  const int bh = blockIdx.y;
  const int start = gstart[g], n = gsz[g];
  const int lane = threadIdx.x;
  const int ql = lane & 15, lg = lane >> 4;

  const size_t planeSz = (size_t)Bc * Hc * Sc * HDc;
  const ushort* qb = qkv + (size_t)bh * Sc * HDc;
  const ushort* kb = qb + planeSz;
  const ushort* vb = kb + planeSz;

  // Q fragments (B-operand): lane holds col q=ql, kdim d = h*32 + lg*8 + (0..7)
  bf16x8 qf[2][2];
#pragma unroll
  for (int qt = 0; qt < 2; ++qt) {
    int row = min(start + q0 + qt * 16 + ql, Sc - 1);
#pragma unroll
    for (int h = 0; h < 2; ++h)
      qf[qt][h] = *(const bf16x8*)(qb + (size_t)row * HDc + h * 32 + lg * 8);
  }

  f32x4 oacc[2][4] = {};  // [qt][dq]: O^T tile, lane holds col q=ql, row d=dq*16+4lg+r
  float lsum[2] = {0.f, 0.f};

  const int vk = lane & 31;          // V staging: row k within 32-tile
  const int vh = (lane >> 5) * 32;   // V staging: d half [vh, vh+32)
  const int Lbase = 4 * (ql + 32 * (lg & 1));  // bpermute source byte addr

  const int npair = (n + 31) >> 5;
  for (int pr = 0; pr < npair; ++pr) {
    const int c0 = pr * 32;
    // issue V global loads early (latency hides under QK + softmax)
    int vrow = min(start + c0 + vk, Sc - 1);
    const uint4* vp = (const uint4*)(vb + (size_t)vrow * HDc + vh);
    uint4 v0 = vp[0], v1 = vp[1], v2 = vp[2], v3 = vp[3];

    // K fragments (A-operand): lane holds row k=ql (in tile), kdim d = h*32+lg*8
    bf16x8 kf[2][2];
#pragma unroll
    for (int t = 0; t < 2; ++t) {
      int row = min(start + c0 + t * 16 + ql, Sc - 1);
#pragma unroll
      for (int h = 0; h < 2; ++h)
        kf[t][h] = *(const bf16x8*)(kb + (size_t)row * HDc + h * 32 + lg * 8);
    }

    uint pw[2][4];
#pragma unroll
    for (int qt = 0; qt < 2; ++qt) {
      f32x4 s0 = {}, s1 = {};
      s0 = __builtin_amdgcn_mfma_f32_16x16x32_bf16(kf[0][0], qf[qt][0], s0, 0, 0, 0);
      s0 = __builtin_amdgcn_mfma_f32_16x16x32_bf16(kf[0][1], qf[qt][1], s0, 0, 0, 0);
      s1 = __builtin_amdgcn_mfma_f32_16x16x32_bf16(kf[1][0], qf[qt][0], s1, 0, 0, 0);
      s1 = __builtin_amdgcn_mfma_f32_16x16x32_bf16(kf[1][1], qf[qt][1], s1, 0, 0, 0);
      float p0[4], p1[4];
      float ls = 0.f;
#pragma unroll
      for (int r = 0; r < 4; ++r) {
        int kk = c0 + 4 * lg + r;
        float e0 = (kk < n) ? __expf(s0[r] * 0.125f) : 0.f;
        float e1 = (kk + 16 < n) ? __expf(s1[r] * 0.125f) : 0.f;
        p0[r] = e0;
        p1[r] = e1;
        ls += e0 + e1;
      }
      lsum[qt] += ls;
      uint a0 = cvtpk(p0[0], p0[1]), b0 = cvtpk(p0[2], p0[3]);
      uint a1 = cvtpk(p1[0], p1[1]), b1 = cvtpk(p1[2], p1[3]);
      // 8 bpermutes: tile chosen by DEST lg>>1 after the pull
      uint pA0 = __builtin_amdgcn_ds_bpermute(Lbase, a0);
      uint pB0 = __builtin_amdgcn_ds_bpermute(Lbase, b0);
      uint pA1 = __builtin_amdgcn_ds_bpermute(Lbase, a1);
      uint pB1 = __builtin_amdgcn_ds_bpermute(Lbase, b1);
      uint pC0 = __builtin_amdgcn_ds_bpermute(Lbase + 64, a0);
      uint pD0 = __builtin_amdgcn_ds_bpermute(Lbase + 64, b0);
      uint pC1 = __builtin_amdgcn_ds_bpermute(Lbase + 64, a1);
      uint pD1 = __builtin_amdgcn_ds_bpermute(Lbase + 64, b1);
      bool t0 = lg < 2;
      pw[qt][0] = t0 ? pA0 : pA1;
      pw[qt][1] = t0 ? pB0 : pB1;
      pw[qt][2] = t0 ? pC0 : pC1;
      pw[qt][3] = t0 ? pD0 : pD1;
    }

    // LDS transpose of V tile: Vt[d][k] <- V[k][d]; full coverage: 32 writes/lane
    {
      uint w[16] = {v0.x, v0.y, v0.z, v0.w, v1.x, v1.y, v1.z, v1.w,
                    v2.x, v2.y, v2.z, v2.w, v3.x, v3.y, v3.z, v3.w};
#pragma unroll
      for (int i = 0; i < 16; ++i) {
        vt[(vh + 2 * i) * 40 + vk] = (ushort)(w[i] & 0xffffu);
        vt[(vh + 2 * i + 1) * 40 + vk] = (ushort)(w[i] >> 16);
      }
    }
    asm volatile("s_waitcnt lgkmcnt(0)" ::: "memory");  // cross-lane write->read (1 wave)
    __builtin_amdgcn_sched_barrier(0);
    bf16x8 vf[4];
#pragma unroll
    for (int dq = 0; dq < 4; ++dq)
      vf[dq] = *(const bf16x8*)(vt + (dq * 16 + ql) * 40 + lg * 8);
    asm volatile("s_waitcnt lgkmcnt(0)" ::: "memory");  // reads done before next-iter writes
    __builtin_amdgcn_sched_barrier(0);
#pragma unroll
    for (int qt = 0; qt < 2; ++qt) {
      union { uint u[4]; bf16x8 v; } pf;
      pf.u[0] = pw[qt][0]; pf.u[1] = pw[qt][1]; pf.u[2] = pw[qt][2]; pf.u[3] = pw[qt][3];
#pragma unroll
      for (int dq = 0; dq < 4; ++dq)
        oacc[qt][dq] = __builtin_amdgcn_mfma_f32_16x16x32_bf16(vf[dq], pf.v, oacc[qt][dq], 0, 0, 0);
    }
  }

  // epilogue: reduce denominator across lane groups, scale, store O^T columns
#pragma unroll
  for (int qt = 0; qt < 2; ++qt) {
    float l = lsum[qt];
    l += __shfl_xor(l, 16);
    l += __shfl_xor(l, 32);
    float inv = 1.f / l;
    int qi = q0 + qt * 16 + ql;
    if (qi < n) {
      int p = start + qi;  // sorted space, contiguous
      ushort* op = obuf + (size_t)((bh >> 3) * Sc + p) * Ec + (bh & 7) * HDc + lg * 4;
#pragma unroll
      for (int dq = 0; dq < 4; ++dq) {
        uint w0 = cvtpk(oacc[qt][dq][0] * inv, oacc[qt][dq][1] * inv);
        uint w1 = cvtpk(oacc[qt][dq][2] * inv, oacc[qt][dq][3] * inv);
        uint2 wv = {w0, w1};
        *(uint2*)(op + dq * 16) = wv;
      }
    }
  }
}

extern "C" void kernel_launch(void* const* d_in, const int* in_sizes, int n_in,
                              void* d_out, int out_size, void* d_ws, size_t ws_size,
                              hipStream_t stream) {
  const float* x  = (const float*)d_in[0];
  const float* Wq = (const float*)d_in[1];
  const float* bq = (const float*)d_in[2];
  const float* Wk = (const float*)d_in[3];
  const float* bk = (const float*)d_in[4];
  const float* Wv = (const float*)d_in[5];
  const float* bv = (const float*)d_in[6];
  const float* Wo = (const float*)d_in[7];
  const float* bo = (const float*)d_in[8];
  const int* ids  = (const int*)d_in[9];
  float* out = (float*)d_out;

  char* ws = (char*)d_ws;
  // layout (bytes): xb 16M | Wcat 1.5M | Wob 0.5M | qkv 48M | obuf 16M | ints
  ushort* xb   = (ushort*)(ws);
  ushort* Wcat = (ushort*)(ws + 16777216);
  ushort* Wob  = (ushort*)(ws + 18350080);
  ushort* qkv  = (ushort*)(ws + 18874368);
  ushort* obuf = (ushort*)(ws + 69206016);
  int* perm    = (int*)(ws + 85983232);
  int* gstart  = perm + Sc;
  int* gsz     = gstart + NI;
  int* items   = gsz + NI;
  int* nitems  = items + MAXITEMS;

  sort_kernel<<<dim3(1), dim3(256), 0, stream>>>(ids, perm, gstart, gsz, items, nitems);
  cvt_x_kernel<<<dim3(Mtot * Ec / 4 / 256), dim3(256), 0, stream>>>(x, perm, xb);
  cvt_w_kernel<<<dim3(2048 * 512 / 4 / 256), dim3(256), 0, stream>>>(Wq, Wk, Wv, Wo, Wcat, Wob);
  gemm_bt<1536, true><<<dim3(Mtot / 128 * 12), dim3(256), 0, stream>>>(
      xb, Wcat, bq, bk, bv, perm, qkv, (float*)nullptr);
  attn5_kernel<<<dim3(MAXITEMS, Bc * Hc), dim3(64), 0, stream>>>(qkv, gstart, gsz, items,
                                                                 nitems, obuf);
  gemm_bt<512, false><<<dim3(Mtot / 128 * 4), dim3(256), 0, stream>>>(
      obuf, Wob, bo, bo, bo, perm, (ushort*)nullptr, out);
}

// Round 8
// 130.316 us; speedup vs baseline: 1.2023x; 1.1861x over previous
//
#include <hip/hip_runtime.h>
#include <cstdint>

#define DEVFN __device__ __forceinline__

typedef __bf16 bf16x8 __attribute__((ext_vector_type(8)));
typedef float f32x4 __attribute__((ext_vector_type(4)));
typedef unsigned int uint;

constexpr int Bc = 8, Sc = 2048, Ec = 512, Hc = 8, HDc = 64, NI = 64;
constexpr int Mtot = Bc * Sc;  // 16384
constexpr int Kdim = Ec;       // 512
constexpr int MAXITEMS = 128;  // sum ceil(n_g/32) <= 64 + 2048/32 = 128

DEVFN unsigned short f2bf(float f) {
  unsigned u = __builtin_bit_cast(unsigned, f);
  u += 0x7fffu + ((u >> 16) & 1u);  // RNE (inputs finite)
  return (unsigned short)(u >> 16);
}

typedef const void __attribute__((address_space(1))) gvoid_t;
typedef void __attribute__((address_space(3))) lvoid_t;
DEVFN void gload16(const void* g, void* l) {
  __builtin_amdgcn_global_load_lds((gvoid_t*)g, (lvoid_t*)l, 16, 0, 0);
}

DEVFN uint cvtpk(float lo, float hi) {
  uint r;
  asm("v_cvt_pk_bf16_f32 %0, %1, %2" : "=v"(r) : "v"(lo), "v"(hi));
  return r;
}

// ---------------- conversions ----------------
// cvt_x permutes tokens into SORTED space: xb[b][p][:] = bf16(x[b][perm[p]][:]).
__global__ void cvt_x_kernel(const float* __restrict__ x, const int* __restrict__ perm,
                             ushort* __restrict__ xb) {
  int i = blockIdx.x * 256 + threadIdx.x;  // 4-float chunk; grid exact
  int mp = i >> 7;                         // row in sorted space (128 chunks/row)
  int c = i & 127;
  int b = mp >> 11, p = mp & (Sc - 1);
  int srow = (b << 11) | perm[p];
  float4 v = *(const float4*)(x + (size_t)srow * Ec + c * 4);
  ushort4 o = {f2bf(v.x), f2bf(v.y), f2bf(v.z), f2bf(v.w)};
  ((ushort4*)xb)[i] = o;
}

__global__ void cvt_w_kernel(const float* __restrict__ Wq, const float* __restrict__ Wk,
                             const float* __restrict__ Wv, const float* __restrict__ Wo,
                             ushort* __restrict__ Wcat, ushort* __restrict__ Wob) {
  int i = blockIdx.x * 256 + threadIdx.x;
  int idx = i * 4;
  int n = idx >> 9, k = idx & 511;
  const float* src;
  ushort* dst;
  if (n < 512)       { src = Wq + (size_t)n * 512 + k;          dst = Wcat + (size_t)n * 512 + k; }
  else if (n < 1024) { src = Wk + (size_t)(n - 512) * 512 + k;  dst = Wcat + (size_t)n * 512 + k; }
  else if (n < 1536) { src = Wv + (size_t)(n - 1024) * 512 + k; dst = Wcat + (size_t)n * 512 + k; }
  else               { src = Wo + (size_t)(n - 1536) * 512 + k; dst = Wob + (size_t)(n - 1536) * 512 + k; }
  float4 v = *(const float4*)src;
  ushort4 o = {f2bf(v.x), f2bf(v.y), f2bf(v.z), f2bf(v.w)};
  *(ushort4*)dst = o;
}

// ---------------- deterministic counting sort by industry + work items ----------------
__global__ void sort_kernel(const int* __restrict__ ids, int* __restrict__ perm,
                            int* __restrict__ gstart, int* __restrict__ gsz,
                            int* __restrict__ items, int* __restrict__ nitems) {
  __shared__ int sid[Sc];
  __shared__ int hist[NI];
  __shared__ int base[NI];
  int t = threadIdx.x;  // 256 threads, 1 block
  if (t < NI) hist[t] = 0;
  for (int i = t; i < Sc; i += 256) sid[i] = ids[i];
  __syncthreads();
  for (int i = t; i < Sc; i += 256) atomicAdd(&hist[sid[i]], 1);
  __syncthreads();
  if (t == 0) {
    int run = 0;
    for (int g = 0; g < NI; ++g) { base[g] = run; run += hist[g]; }
    int cnt = 0;
    for (int g = 0; g < NI; ++g)
      for (int q0 = 0; q0 < hist[g]; q0 += 32) items[cnt++] = (g << 16) | q0;
    *nitems = cnt;
  }
  __syncthreads();
  if (t < NI) { gstart[t] = base[t]; gsz[t] = hist[t]; }
  int lane = t & 63, w = t >> 6;
  for (int g = w; g < NI; g += 4) {
    int run = base[g];
    for (int c = 0; c < Sc; c += 64) {
      int tok = c + lane;
      int id = sid[tok];
      unsigned long long mask = __ballot(id == g);
      if (id == g) {
        int rank = __popcll(mask & ((1ull << lane) - 1ull));
        perm[run + rank] = tok;
      }
      run += __popcll(mask);
    }
  }
}

// ---------------- 128x128 bf16 MFMA GEMM, 2-phase dbuf + LDS-bounce epilogue ----
// K-loop identical to round 7 (proven). Epilogue: acc -> LDS tile (reusing the
// 64KB staging buffer after the final barrier) -> coalesced 16B global stores.
// QKV: 8x global_store_dwordx4/thread (was 64x 2B scatter); full-line coverage
// kills write-allocate fills. OUT: 16x float4 stores (rows scattered via perm).
template <int NTOT, bool QKV>
__global__ __launch_bounds__(256) void gemm_bt(
    const ushort* __restrict__ A, const ushort* __restrict__ Bw,
    const float* __restrict__ bias0, const float* __restrict__ bias1,
    const float* __restrict__ bias2, const int* __restrict__ permarg,
    ushort* __restrict__ qkvout, float* __restrict__ out) {
  __shared__ __align__(16) char ldsraw[65536];
  ushort* sAb = (ushort*)ldsraw;             // [2][128*64]
  ushort* sBb = (ushort*)(ldsraw + 32768);   // [2][128*64]
  const int tid = threadIdx.x;
  const int lane = tid & 63;
  const int wave = tid >> 6;
  const int wr = wave >> 1, wc = wave & 1;
  // XCD-locality swizzle (blockIdx round-robins across 8 XCDs)
  const int orig = blockIdx.x;
  const int xcd = orig & 7, gl = orig >> 3;
  const int mbase = (xcd * 16 + (gl & 15)) * 128;
  const int nbase = (gl >> 4) * 128;

  f32x4 acc[4][4] = {};

  const int rowS = wave * 32 + (lane >> 3);  // staging row (+ c*8)
  const int kc = lane & 7;                   // staging 16B chunk within row

  auto stage = [&](int buf, int kt) {
    const int k0 = kt * 64;
#pragma unroll
    for (int c = 0; c < 4; ++c) {
      int row = rowS + c * 8;
      int kcp = (kc ^ (row & 7)) * 8;  // pre-swizzled source -> linear LDS dest
      gload16(A + (size_t)(mbase + row) * Kdim + k0 + kcp,
              sAb + buf * 8192 + (wave * 256 + c * 64) * 8);
      gload16(Bw + (size_t)(nbase + row) * Kdim + k0 + kcp,
              sBb + buf * 8192 + (wave * 256 + c * 64) * 8);
    }
  };

  stage(0, 0);
  __syncthreads();

  for (int kt = 0; kt < Kdim / 64; ++kt) {
    const int cur = kt & 1;
    if (kt + 1 < Kdim / 64) stage(cur ^ 1, kt + 1);
    const char* Ab = (const char*)(sAb + cur * 8192);
    const char* Bb = (const char*)(sBb + cur * 8192);
#pragma unroll
    for (int kk = 0; kk < 2; ++kk) {
      bf16x8 af[4], bfv[4];
#pragma unroll
      for (int i = 0; i < 4; ++i) {
        int row = wr * 64 + i * 16 + (lane & 15);
        int off = row * 128 + kk * 64 + (lane >> 4) * 16;
        off ^= (row & 7) << 4;
        af[i] = *(const bf16x8*)(Ab + off);
      }
#pragma unroll
      for (int j = 0; j < 4; ++j) {
        int col = wc * 64 + j * 16 + (lane & 15);
        int off = col * 128 + kk * 64 + (lane >> 4) * 16;
        off ^= (col & 7) << 4;
        bfv[j] = *(const bf16x8*)(Bb + off);
      }
#pragma unroll
      for (int i = 0; i < 4; ++i)
#pragma unroll
        for (int j = 0; j < 4; ++j)
          acc[i][j] = __builtin_amdgcn_mfma_f32_16x16x32_bf16(af[i], bfv[j], acc[i][j], 0, 0, 0);
    }
    __syncthreads();  // single barrier/iter: next buffer staged + read-safety
  }

  // ---------------- LDS-bounce epilogue ----------------
  if constexpr (QKV) {
    ushort* T = (ushort*)ldsraw;  // [128][136] (272B rows: 16B-aligned, <=2-way banks)
#pragma unroll
    for (int i = 0; i < 4; ++i) {
#pragma unroll
      for (int j = 0; j < 4; ++j) {
        int nl = wc * 64 + j * 16 + (lane & 15);
        int n = nbase + nl;
        float bv = (n < 512) ? bias0[n] : (n < 1024) ? bias1[n - 512] : bias2[n - 1024];
#pragma unroll
        for (int r = 0; r < 4; ++r) {
          int ml = wr * 64 + i * 16 + (lane >> 4) * 4 + r;
          T[ml * 136 + nl] = f2bf(acc[i][j][r] + bv);
        }
      }
    }
    __syncthreads();
#pragma unroll
    for (int k = 0; k < 8; ++k) {
      int c = tid + 256 * k;
      int row = c >> 4, col8 = (c & 15) * 8;
      uint4 w = *(const uint4*)(T + row * 136 + col8);
      int n0 = nbase + col8;
      int proj = n0 >> 9, h = (n0 >> 6) & 7, d0 = n0 & 63;
      int p = mbase + row;
      int bidx = p >> 11, pl = p & (Sc - 1);
      size_t off = (size_t)proj * ((size_t)Bc * Hc * Sc * HDc) +
                   (size_t)((bidx * Hc + h) * Sc + pl) * HDc + d0;
      *(uint4*)(qkvout + off) = w;  // coalesced 16B, full-line coverage
    }
  } else {
    float* T = (float*)ldsraw;  // [128][128] f32 (64KB exactly)
#pragma unroll
    for (int i = 0; i < 4; ++i) {
#pragma unroll
      for (int j = 0; j < 4; ++j) {
        int nl = wc * 64 + j * 16 + (lane & 15);
        float bv = bias0[nbase + nl];
#pragma unroll
        for (int r = 0; r < 4; ++r) {
          int ml = wr * 64 + i * 16 + (lane >> 4) * 4 + r;
          T[ml * 128 + nl] = acc[i][j][r] + bv;
        }
      }
    }
    __syncthreads();
#pragma unroll
    for (int k = 0; k < 16; ++k) {
      int c = tid + 256 * k;
      int row = c >> 5, col4 = (c & 31) * 4;
      float4 w = *(const float4*)(T + row * 128 + col4);
      int p = mbase + row;
      int bidx = p >> 11;
      int orow = (bidx << 11) | permarg[p & (Sc - 1)];  // scatter back to token order
      *(float4*)(out + (size_t)orow * NTOT + nbase + col4) = w;
    }
  }
}

// ---------------- MFMA attention: 1 wave = (bh, 32-query chunk of one group) -------
__global__ __launch_bounds__(64) void attn5_kernel(
    const ushort* __restrict__ qkv, const int* __restrict__ gstart,
    const int* __restrict__ gsz, const int* __restrict__ items,
    const int* __restrict__ nitems, ushort* __restrict__ obuf) {
  __shared__ __align__(16) ushort vt[64 * 40];  // Vt[d][k], rows padded to 40 ushorts (80B)
  if ((int)blockIdx.x >= *nitems) return;
  const int iv = items[blockIdx.x];
  const int g = iv >> 16, q0 = iv & 0xffff;
  const int bh = blockIdx.y;
  const int start = gstart[g], n = gsz[g];
  const int lane = threadIdx.x;
  const int ql = lane & 15, lg = lane >> 4;

  const size_t planeSz = (size_t)Bc * Hc * Sc * HDc;
  const ushort* qb = qkv + (size_t)bh * Sc * HDc;
  const ushort* kb = qb + planeSz;
  const ushort* vb = kb + planeSz;

  bf16x8 qf[2][2];
#pragma unroll
  for (int qt = 0; qt < 2; ++qt) {
    int row = min(start + q0 + qt * 16 + ql, Sc - 1);
#pragma unroll
    for (int h = 0; h < 2; ++h)
      qf[qt][h] = *(const bf16x8*)(qb + (size_t)row * HDc + h * 32 + lg * 8);
  }

  f32x4 oacc[2][4] = {};
  float lsum[2] = {0.f, 0.f};

  const int vk = lane & 31;
  const int vh = (lane >> 5) * 32;
  const int Lbase = 4 * (ql + 32 * (lg & 1));

  const int npair = (n + 31) >> 5;
  for (int pr = 0; pr < npair; ++pr) {
    const int c0 = pr * 32;
    int vrow = min(start + c0 + vk, Sc - 1);
    const uint4* vp = (const uint4*)(vb + (size_t)vrow * HDc + vh);
    uint4 v0 = vp[0], v1 = vp[1], v2 = vp[2], v3 = vp[3];

    bf16x8 kf[2][2];
#pragma unroll
    for (int t = 0; t < 2; ++t) {
      int row = min(start + c0 + t * 16 + ql, Sc - 1);
#pragma unroll
      for (int h = 0; h < 2; ++h)
        kf[t][h] = *(const bf16x8*)(kb + (size_t)row * HDc + h * 32 + lg * 8);
    }

    uint pw[2][4];
#pragma unroll
    for (int qt = 0; qt < 2; ++qt) {
      f32x4 s0 = {}, s1 = {};
      s0 = __builtin_amdgcn_mfma_f32_16x16x32_bf16(kf[0][0], qf[qt][0], s0, 0, 0, 0);
      s0 = __builtin_amdgcn_mfma_f32_16x16x32_bf16(kf[0][1], qf[qt][1], s0, 0, 0, 0);
      s1 = __builtin_amdgcn_mfma_f32_16x16x32_bf16(kf[1][0], qf[qt][0], s1, 0, 0, 0);
      s1 = __builtin_amdgcn_mfma_f32_16x16x32_bf16(kf[1][1], qf[qt][1], s1, 0, 0, 0);
      float p0[4], p1[4];
      float ls = 0.f;
#pragma unroll
      for (int r = 0; r < 4; ++r) {
        int kk = c0 + 4 * lg + r;
        float e0 = (kk < n) ? __expf(s0[r] * 0.125f) : 0.f;
        float e1 = (kk + 16 < n) ? __expf(s1[r] * 0.125f) : 0.f;
        p0[r] = e0;
        p1[r] = e1;
        ls += e0 + e1;
      }
      lsum[qt] += ls;
      uint a0 = cvtpk(p0[0], p0[1]), b0 = cvtpk(p0[2], p0[3]);
      uint a1 = cvtpk(p1[0], p1[1]), b1 = cvtpk(p1[2], p1[3]);
      uint pA0 = __builtin_amdgcn_ds_bpermute(Lbase, a0);
      uint pB0 = __builtin_amdgcn_ds_bpermute(Lbase, b0);
      uint pA1 = __builtin_amdgcn_ds_bpermute(Lbase, a1);
      uint pB1 = __builtin_amdgcn_ds_bpermute(Lbase, b1);
      uint pC0 = __builtin_amdgcn_ds_bpermute(Lbase + 64, a0);
      uint pD0 = __builtin_amdgcn_ds_bpermute(Lbase + 64, b0);
      uint pC1 = __builtin_amdgcn_ds_bpermute(Lbase + 64, a1);
      uint pD1 = __builtin_amdgcn_ds_bpermute(Lbase + 64, b1);
      bool t0 = lg < 2;
      pw[qt][0] = t0 ? pA0 : pA1;
      pw[qt][1] = t0 ? pB0 : pB1;
      pw[qt][2] = t0 ? pC0 : pC1;
      pw[qt][3] = t0 ? pD0 : pD1;
    }

    {
      uint w[16] = {v0.x, v0.y, v0.z, v0.w, v1.x, v1.y, v1.z, v1.w,
                    v2.x, v2.y, v2.z, v2.w, v3.x, v3.y, v3.z, v3.w};
#pragma unroll
      for (int i = 0; i < 16; ++i) {
        vt[(vh + 2 * i) * 40 + vk] = (ushort)(w[i] & 0xffffu);
        vt[(vh + 2 * i + 1) * 40 + vk] = (ushort)(w[i] >> 16);
      }
    }
    asm volatile("s_waitcnt lgkmcnt(0)" ::: "memory");
    __builtin_amdgcn_sched_barrier(0);
    bf16x8 vf[4];
#pragma unroll
    for (int dq = 0; dq < 4; ++dq)
      vf[dq] = *(const bf16x8*)(vt + (dq * 16 + ql) * 40 + lg * 8);
    asm volatile("s_waitcnt lgkmcnt(0)" ::: "memory");
    __builtin_amdgcn_sched_barrier(0);
#pragma unroll
    for (int qt = 0; qt < 2; ++qt) {
      union { uint u[4]; bf16x8 v; } pf;
      pf.u[0] = pw[qt][0]; pf.u[1] = pw[qt][1]; pf.u[2] = pw[qt][2]; pf.u[3] = pw[qt][3];
#pragma unroll
      for (int dq = 0; dq < 4; ++dq)
        oacc[qt][dq] = __builtin_amdgcn_mfma_f32_16x16x32_bf16(vf[dq], pf.v, oacc[qt][dq], 0, 0, 0);
    }
  }

#pragma unroll
  for (int qt = 0; qt < 2; ++qt) {
    float l = lsum[qt];
    l += __shfl_xor(l, 16);
    l += __shfl_xor(l, 32);
    float inv = 1.f / l;
    int qi = q0 + qt * 16 + ql;
    if (qi < n) {
      int p = start + qi;  // sorted space, contiguous
      ushort* op = obuf + (size_t)((bh >> 3) * Sc + p) * Ec + (bh & 7) * HDc + lg * 4;
#pragma unroll
      for (int dq = 0; dq < 4; ++dq) {
        uint w0 = cvtpk(oacc[qt][dq][0] * inv, oacc[qt][dq][1] * inv);
        uint w1 = cvtpk(oacc[qt][dq][2] * inv, oacc[qt][dq][3] * inv);
        uint2 wv = {w0, w1};
        *(uint2*)(op + dq * 16) = wv;
      }
    }
  }
}

extern "C" void kernel_launch(void* const* d_in, const int* in_sizes, int n_in,
                              void* d_out, int out_size, void* d_ws, size_t ws_size,
                              hipStream_t stream) {
  const float* x  = (const float*)d_in[0];
  const float* Wq = (const float*)d_in[1];
  const float* bq = (const float*)d_in[2];
  const float* Wk = (const float*)d_in[3];
  const float* bk = (const float*)d_in[4];
  const float* Wv = (const float*)d_in[5];
  const float* bv = (const float*)d_in[6];
  const float* Wo = (const float*)d_in[7];
  const float* bo = (const float*)d_in[8];
  const int* ids  = (const int*)d_in[9];
  float* out = (float*)d_out;

  char* ws = (char*)d_ws;
  ushort* xb   = (ushort*)(ws);
  ushort* Wcat = (ushort*)(ws + 16777216);
  ushort* Wob  = (ushort*)(ws + 18350080);
  ushort* qkv  = (ushort*)(ws + 18874368);
  ushort* obuf = (ushort*)(ws + 69206016);
  int* perm    = (int*)(ws + 85983232);
  int* gstart  = perm + Sc;
  int* gsz     = gstart + NI;
  int* items   = gsz + NI;
  int* nitems  = items + MAXITEMS;

  sort_kernel<<<dim3(1), dim3(256), 0, stream>>>(ids, perm, gstart, gsz, items, nitems);
  cvt_x_kernel<<<dim3(Mtot * Ec / 4 / 256), dim3(256), 0, stream>>>(x, perm, xb);
  cvt_w_kernel<<<dim3(2048 * 512 / 4 / 256), dim3(256), 0, stream>>>(Wq, Wk, Wv, Wo, Wcat, Wob);
  gemm_bt<1536, true><<<dim3(Mtot / 128 * 12), dim3(256), 0, stream>>>(
      xb, Wcat, bq, bk, bv, perm, qkv, (float*)nullptr);
  attn5_kernel<<<dim3(MAXITEMS, Bc * Hc), dim3(64), 0, stream>>>(qkv, gstart, gsz, items,
                                                                 nitems, obuf);
  gemm_bt<512, false><<<dim3(Mtot / 128 * 4), dim3(256), 0, stream>>>(
      obuf, Wob, bo, bo, bo, perm, (ushort*)nullptr, out);
}

// Round 9
// 128.524 us; speedup vs baseline: 1.2190x; 1.0139x over previous
//
#include <hip/hip_runtime.h>
#include <cstdint>

#define DEVFN __device__ __forceinline__

typedef __bf16 bf16x8 __attribute__((ext_vector_type(8)));
typedef float f32x4 __attribute__((ext_vector_type(4)));
typedef unsigned int uint;

constexpr int Bc = 8, Sc = 2048, Ec = 512, Hc = 8, HDc = 64, NI = 64;
constexpr int Mtot = Bc * Sc;  // 16384
constexpr int Kdim = Ec;       // 512
constexpr int MAXITEMS = 128;  // sum ceil(n_g/32) <= 64 + 2048/32 = 128

DEVFN unsigned short f2bf(float f) {
  unsigned u = __builtin_bit_cast(unsigned, f);
  u += 0x7fffu + ((u >> 16) & 1u);  // RNE (inputs finite)
  return (unsigned short)(u >> 16);
}

typedef const void __attribute__((address_space(1))) gvoid_t;
typedef void __attribute__((address_space(3))) lvoid_t;
DEVFN void gload16(const void* g, void* l) {
  __builtin_amdgcn_global_load_lds((gvoid_t*)g, (lvoid_t*)l, 16, 0, 0);
}

DEVFN uint cvtpk(float lo, float hi) {
  uint r;
  asm("v_cvt_pk_bf16_f32 %0, %1, %2" : "=v"(r) : "v"(lo), "v"(hi));
  return r;
}

// ---------------- conversions ----------------
// cvt_x permutes tokens into SORTED space: xb[b][p][:] = bf16(x[b][perm[p]][:]).
__global__ void cvt_x_kernel(const float* __restrict__ x, const int* __restrict__ perm,
                             ushort* __restrict__ xb) {
  int i = blockIdx.x * 256 + threadIdx.x;  // 4-float chunk; grid exact
  int mp = i >> 7;                         // row in sorted space (128 chunks/row)
  int c = i & 127;
  int b = mp >> 11, p = mp & (Sc - 1);
  int srow = (b << 11) | perm[p];
  float4 v = *(const float4*)(x + (size_t)srow * Ec + c * 4);
  ushort4 o = {f2bf(v.x), f2bf(v.y), f2bf(v.z), f2bf(v.w)};
  ((ushort4*)xb)[i] = o;
}

__global__ void cvt_w_kernel(const float* __restrict__ Wq, const float* __restrict__ Wk,
                             const float* __restrict__ Wv, const float* __restrict__ Wo,
                             ushort* __restrict__ Wcat, ushort* __restrict__ Wob) {
  int i = blockIdx.x * 256 + threadIdx.x;
  int idx = i * 4;
  int n = idx >> 9, k = idx & 511;
  const float* src;
  ushort* dst;
  if (n < 512)       { src = Wq + (size_t)n * 512 + k;          dst = Wcat + (size_t)n * 512 + k; }
  else if (n < 1024) { src = Wk + (size_t)(n - 512) * 512 + k;  dst = Wcat + (size_t)n * 512 + k; }
  else if (n < 1536) { src = Wv + (size_t)(n - 1024) * 512 + k; dst = Wcat + (size_t)n * 512 + k; }
  else               { src = Wo + (size_t)(n - 1536) * 512 + k; dst = Wob + (size_t)(n - 1536) * 512 + k; }
  float4 v = *(const float4*)src;
  ushort4 o = {f2bf(v.x), f2bf(v.y), f2bf(v.z), f2bf(v.w)};
  *(ushort4*)dst = o;
}

// ---------------- deterministic counting sort by industry + work items ----------------
__global__ void sort_kernel(const int* __restrict__ ids, int* __restrict__ perm,
                            int* __restrict__ gstart, int* __restrict__ gsz,
                            int* __restrict__ items, int* __restrict__ nitems) {
  __shared__ int sid[Sc];
  __shared__ int hist[NI];
  __shared__ int base[NI];
  int t = threadIdx.x;  // 256 threads, 1 block
  if (t < NI) hist[t] = 0;
  for (int i = t; i < Sc; i += 256) sid[i] = ids[i];
  __syncthreads();
  for (int i = t; i < Sc; i += 256) atomicAdd(&hist[sid[i]], 1);
  __syncthreads();
  if (t == 0) {
    int run = 0;
    for (int g = 0; g < NI; ++g) { base[g] = run; run += hist[g]; }
    int cnt = 0;
    for (int g = 0; g < NI; ++g)
      for (int q0 = 0; q0 < hist[g]; q0 += 32) items[cnt++] = (g << 16) | q0;
    *nitems = cnt;
  }
  __syncthreads();
  if (t < NI) { gstart[t] = base[t]; gsz[t] = hist[t]; }
  int lane = t & 63, w = t >> 6;
  for (int g = w; g < NI; g += 4) {
    int run = base[g];
    for (int c = 0; c < Sc; c += 64) {
      int tok = c + lane;
      int id = sid[tok];
      unsigned long long mask = __ballot(id == g);
      if (id == g) {
        int rank = __popcll(mask & ((1ull << lane) - 1ull));
        perm[run + rank] = tok;
      }
      run += __popcll(mask);
    }
  }
}

// ---------------- 128x128 bf16 MFMA GEMM: counted-vmcnt 2-deep pipeline ----------
// T3+T4: prologue stages tiles 0,1. Per K-step: vmcnt(8) (my tile-kt loads done,
// tile-kt+1's 8 stay IN FLIGHT) -> s_barrier -> ds_read+MFMA -> lgkmcnt(0) ->
// s_barrier -> stage tile kt+2 into the buffer just read. No vmcnt(0) drain in
// the main loop. Epilogue: LDS-bounce -> coalesced 16B stores (round 8, proven).
template <int NTOT, bool QKV>
__global__ __launch_bounds__(256) void gemm_bt(
    const ushort* __restrict__ A, const ushort* __restrict__ Bw,
    const float* __restrict__ bias0, const float* __restrict__ bias1,
    const float* __restrict__ bias2, const int* __restrict__ permarg,
    ushort* __restrict__ qkvout, float* __restrict__ out) {
  constexpr int NK = Kdim / 64;  // 8
  __shared__ __align__(16) char ldsraw[65536];
  ushort* sAb = (ushort*)ldsraw;             // [2][128*64]
  ushort* sBb = (ushort*)(ldsraw + 32768);   // [2][128*64]
  const int tid = threadIdx.x;
  const int lane = tid & 63;
  const int wave = tid >> 6;
  const int wr = wave >> 1, wc = wave & 1;
  // XCD-locality swizzle (blockIdx round-robins across 8 XCDs)
  const int orig = blockIdx.x;
  const int xcd = orig & 7, gl = orig >> 3;
  const int mbase = (xcd * 16 + (gl & 15)) * 128;
  const int nbase = (gl >> 4) * 128;

  f32x4 acc[4][4] = {};

  const int rowS = wave * 32 + (lane >> 3);  // staging row (+ c*8)
  const int kc = lane & 7;                   // staging 16B chunk within row

  auto stage = [&](int buf, int kt) {  // 8 gload16 per thread (4 A + 4 B)
    const int k0 = kt * 64;
#pragma unroll
    for (int c = 0; c < 4; ++c) {
      int row = rowS + c * 8;
      int kcp = (kc ^ (row & 7)) * 8;  // pre-swizzled source -> linear LDS dest
      gload16(A + (size_t)(mbase + row) * Kdim + k0 + kcp,
              sAb + buf * 8192 + (wave * 256 + c * 64) * 8);
      gload16(Bw + (size_t)(nbase + row) * Kdim + k0 + kcp,
              sBb + buf * 8192 + (wave * 256 + c * 64) * 8);
    }
  };

  stage(0, 0);
  stage(1, 1);  // 16 loads in flight

  for (int kt = 0; kt < NK; ++kt) {
    const int cur = kt & 1;
    // my tile-kt loads complete; tile-kt+1's 8 newest may remain in flight
    if (kt < NK - 1) {
      asm volatile("s_waitcnt vmcnt(8)" ::: "memory");
    } else {
      asm volatile("s_waitcnt vmcnt(0)" ::: "memory");
    }
    __builtin_amdgcn_sched_barrier(0);
    __builtin_amdgcn_s_barrier();  // everyone's tile-kt data visible in LDS
    __builtin_amdgcn_sched_barrier(0);

    const char* Ab = (const char*)(sAb + cur * 8192);
    const char* Bb = (const char*)(sBb + cur * 8192);
    __builtin_amdgcn_s_setprio(1);
#pragma unroll
    for (int kk = 0; kk < 2; ++kk) {
      bf16x8 af[4], bfv[4];
#pragma unroll
      for (int i = 0; i < 4; ++i) {
        int row = wr * 64 + i * 16 + (lane & 15);
        int off = row * 128 + kk * 64 + (lane >> 4) * 16;
        off ^= (row & 7) << 4;
        af[i] = *(const bf16x8*)(Ab + off);
      }
#pragma unroll
      for (int j = 0; j < 4; ++j) {
        int col = wc * 64 + j * 16 + (lane & 15);
        int off = col * 128 + kk * 64 + (lane >> 4) * 16;
        off ^= (col & 7) << 4;
        bfv[j] = *(const bf16x8*)(Bb + off);
      }
#pragma unroll
      for (int i = 0; i < 4; ++i)
#pragma unroll
        for (int j = 0; j < 4; ++j)
          acc[i][j] = __builtin_amdgcn_mfma_f32_16x16x32_bf16(af[i], bfv[j], acc[i][j], 0, 0, 0);
    }
    __builtin_amdgcn_s_setprio(0);

    asm volatile("s_waitcnt lgkmcnt(0)" ::: "memory");  // all my reads of buf cur done
    __builtin_amdgcn_sched_barrier(0);
    __builtin_amdgcn_s_barrier();  // all waves done reading buf cur
    __builtin_amdgcn_sched_barrier(0);
    if (kt + 2 < NK) stage(cur, kt + 2);  // overwrite just-read buffer
  }

  // ---------------- LDS-bounce epilogue (all staging drained: vmcnt(0) at kt=NK-1) ----
  if constexpr (QKV) {
    ushort* T = (ushort*)ldsraw;  // [128][136] (272B rows: 16B-aligned, <=2-way banks)
#pragma unroll
    for (int i = 0; i < 4; ++i) {
#pragma unroll
      for (int j = 0; j < 4; ++j) {
        int nl = wc * 64 + j * 16 + (lane & 15);
        int n = nbase + nl;
        float bv = (n < 512) ? bias0[n] : (n < 1024) ? bias1[n - 512] : bias2[n - 1024];
#pragma unroll
        for (int r = 0; r < 4; ++r) {
          int ml = wr * 64 + i * 16 + (lane >> 4) * 4 + r;
          T[ml * 136 + nl] = f2bf(acc[i][j][r] + bv);
        }
      }
    }
    __syncthreads();
#pragma unroll
    for (int k = 0; k < 8; ++k) {
      int c = tid + 256 * k;
      int row = c >> 4, col8 = (c & 15) * 8;
      uint4 w = *(const uint4*)(T + row * 136 + col8);
      int n0 = nbase + col8;
      int proj = n0 >> 9, h = (n0 >> 6) & 7, d0 = n0 & 63;
      int p = mbase + row;
      int bidx = p >> 11, pl = p & (Sc - 1);
      size_t off = (size_t)proj * ((size_t)Bc * Hc * Sc * HDc) +
                   (size_t)((bidx * Hc + h) * Sc + pl) * HDc + d0;
      *(uint4*)(qkvout + off) = w;  // coalesced 16B, full-line coverage
    }
  } else {
    float* T = (float*)ldsraw;  // [128][128] f32 (64KB exactly)
#pragma unroll
    for (int i = 0; i < 4; ++i) {
#pragma unroll
      for (int j = 0; j < 4; ++j) {
        int nl = wc * 64 + j * 16 + (lane & 15);
        float bv = bias0[nbase + nl];
#pragma unroll
        for (int r = 0; r < 4; ++r) {
          int ml = wr * 64 + i * 16 + (lane >> 4) * 4 + r;
          T[ml * 128 + nl] = acc[i][j][r] + bv;
        }
      }
    }
    __syncthreads();
#pragma unroll
    for (int k = 0; k < 16; ++k) {
      int c = tid + 256 * k;
      int row = c >> 5, col4 = (c & 31) * 4;
      float4 w = *(const float4*)(T + row * 128 + col4);
      int p = mbase + row;
      int bidx = p >> 11;
      int orow = (bidx << 11) | permarg[p & (Sc - 1)];  // scatter back to token order
      *(float4*)(out + (size_t)orow * NTOT + nbase + col4) = w;
    }
  }
}

// ---------------- MFMA attention: 1 wave = (bh, 32-query chunk of one group) -------
__global__ __launch_bounds__(64) void attn5_kernel(
    const ushort* __restrict__ qkv, const int* __restrict__ gstart,
    const int* __restrict__ gsz, const int* __restrict__ items,
    const int* __restrict__ nitems, ushort* __restrict__ obuf) {
  __shared__ __align__(16) ushort vt[64 * 40];  // Vt[d][k], rows padded to 40 ushorts (80B)
  if ((int)blockIdx.x >= *nitems) return;
  const int iv = items[blockIdx.x];
  const int g = iv >> 16, q0 = iv & 0xffff;
  const int bh = blockIdx.y;
  const int start = gstart[g], n = gsz[g];
  const int lane = threadIdx.x;
  const int ql = lane & 15, lg = lane >> 4;

  const size_t planeSz = (size_t)Bc * Hc * Sc * HDc;
  const ushort* qb = qkv + (size_t)bh * Sc * HDc;
  const ushort* kb = qb + planeSz;
  const ushort* vb = kb + planeSz;

  bf16x8 qf[2][2];
#pragma unroll
  for (int qt = 0; qt < 2; ++qt) {
    int row = min(start + q0 + qt * 16 + ql, Sc - 1);
#pragma unroll
    for (int h = 0; h < 2; ++h)
      qf[qt][h] = *(const bf16x8*)(qb + (size_t)row * HDc + h * 32 + lg * 8);
  }

  f32x4 oacc[2][4] = {};
  float lsum[2] = {0.f, 0.f};

  const int vk = lane & 31;
  const int vh = (lane >> 5) * 32;
  const int Lbase = 4 * (ql + 32 * (lg & 1));

  const int npair = (n + 31) >> 5;
  for (int pr = 0; pr < npair; ++pr) {
    const int c0 = pr * 32;
    int vrow = min(start + c0 + vk, Sc - 1);
    const uint4* vp = (const uint4*)(vb + (size_t)vrow * HDc + vh);
    uint4 v0 = vp[0], v1 = vp[1], v2 = vp[2], v3 = vp[3];

    bf16x8 kf[2][2];
#pragma unroll
    for (int t = 0; t < 2; ++t) {
      int row = min(start + c0 + t * 16 + ql, Sc - 1);
#pragma unroll
      for (int h = 0; h < 2; ++h)
        kf[t][h] = *(const bf16x8*)(kb + (size_t)row * HDc + h * 32 + lg * 8);
    }

    uint pw[2][4];
#pragma unroll
    for (int qt = 0; qt < 2; ++qt) {
      f32x4 s0 = {}, s1 = {};
      s0 = __builtin_amdgcn_mfma_f32_16x16x32_bf16(kf[0][0], qf[qt][0], s0, 0, 0, 0);
      s0 = __builtin_amdgcn_mfma_f32_16x16x32_bf16(kf[0][1], qf[qt][1], s0, 0, 0, 0);
      s1 = __builtin_amdgcn_mfma_f32_16x16x32_bf16(kf[1][0], qf[qt][0], s1, 0, 0, 0);
      s1 = __builtin_amdgcn_mfma_f32_16x16x32_bf16(kf[1][1], qf[qt][1], s1, 0, 0, 0);
      float p0[4], p1[4];
      float ls = 0.f;
#pragma unroll
      for (int r = 0; r < 4; ++r) {
        int kk = c0 + 4 * lg + r;
        float e0 = (kk < n) ? __expf(s0[r] * 0.125f) : 0.f;
        float e1 = (kk + 16 < n) ? __expf(s1[r] * 0.125f) : 0.f;
        p0[r] = e0;
        p1[r] = e1;
        ls += e0 + e1;
      }
      lsum[qt] += ls;
      uint a0 = cvtpk(p0[0], p0[1]), b0 = cvtpk(p0[2], p0[3]);
      uint a1 = cvtpk(p1[0], p1[1]), b1 = cvtpk(p1[2], p1[3]);
      uint pA0 = __builtin_amdgcn_ds_bpermute(Lbase, a0);
      uint pB0 = __builtin_amdgcn_ds_bpermute(Lbase, b0);
      uint pA1 = __builtin_amdgcn_ds_bpermute(Lbase, a1);
      uint pB1 = __builtin_amdgcn_ds_bpermute(Lbase, b1);
      uint pC0 = __builtin_amdgcn_ds_bpermute(Lbase + 64, a0);
      uint pD0 = __builtin_amdgcn_ds_bpermute(Lbase + 64, b0);
      uint pC1 = __builtin_amdgcn_ds_bpermute(Lbase + 64, a1);
      uint pD1 = __builtin_amdgcn_ds_bpermute(Lbase + 64, b1);
      bool t0 = lg < 2;
      pw[qt][0] = t0 ? pA0 : pA1;
      pw[qt][1] = t0 ? pB0 : pB1;
      pw[qt][2] = t0 ? pC0 : pC1;
      pw[qt][3] = t0 ? pD0 : pD1;
    }

    {
      uint w[16] = {v0.x, v0.y, v0.z, v0.w, v1.x, v1.y, v1.z, v1.w,
                    v2.x, v2.y, v2.z, v2.w, v3.x, v3.y, v3.z, v3.w};
#pragma unroll
      for (int i = 0; i < 16; ++i) {
        vt[(vh + 2 * i) * 40 + vk] = (ushort)(w[i] & 0xffffu);
        vt[(vh + 2 * i + 1) * 40 + vk] = (ushort)(w[i] >> 16);
      }
    }
    asm volatile("s_waitcnt lgkmcnt(0)" ::: "memory");
    __builtin_amdgcn_sched_barrier(0);
    bf16x8 vf[4];
#pragma unroll
    for (int dq = 0; dq < 4; ++dq)
      vf[dq] = *(const bf16x8*)(vt + (dq * 16 + ql) * 40 + lg * 8);
    asm volatile("s_waitcnt lgkmcnt(0)" ::: "memory");
    __builtin_amdgcn_sched_barrier(0);
#pragma unroll
    for (int qt = 0; qt < 2; ++qt) {
      union { uint u[4]; bf16x8 v; } pf;
      pf.u[0] = pw[qt][0]; pf.u[1] = pw[qt][1]; pf.u[2] = pw[qt][2]; pf.u[3] = pw[qt][3];
#pragma unroll
      for (int dq = 0; dq < 4; ++dq)
        oacc[qt][dq] = __builtin_amdgcn_mfma_f32_16x16x32_bf16(vf[dq], pf.v, oacc[qt][dq], 0, 0, 0);
    }
  }

#pragma unroll
  for (int qt = 0; qt < 2; ++qt) {
    float l = lsum[qt];
    l += __shfl_xor(l, 16);
    l += __shfl_xor(l, 32);
    float inv = 1.f / l;
    int qi = q0 + qt * 16 + ql;
    if (qi < n) {
      int p = start + qi;  // sorted space, contiguous
      ushort* op = obuf + (size_t)((bh >> 3) * Sc + p) * Ec + (bh & 7) * HDc + lg * 4;
#pragma unroll
      for (int dq = 0; dq < 4; ++dq) {
        uint w0 = cvtpk(oacc[qt][dq][0] * inv, oacc[qt][dq][1] * inv);
        uint w1 = cvtpk(oacc[qt][dq][2] * inv, oacc[qt][dq][3] * inv);
        uint2 wv = {w0, w1};
        *(uint2*)(op + dq * 16) = wv;
      }
    }
  }
}

extern "C" void kernel_launch(void* const* d_in, const int* in_sizes, int n_in,
                              void* d_out, int out_size, void* d_ws, size_t ws_size,
                              hipStream_t stream) {
  const float* x  = (const float*)d_in[0];
  const float* Wq = (const float*)d_in[1];
  const float* bq = (const float*)d_in[2];
  const float* Wk = (const float*)d_in[3];
  const float* bk = (const float*)d_in[4];
  const float* Wv = (const float*)d_in[5];
  const float* bv = (const float*)d_in[6];
  const float* Wo = (const float*)d_in[7];
  const float* bo = (const float*)d_in[8];
  const int* ids  = (const int*)d_in[9];
  float* out = (float*)d_out;

  char* ws = (char*)d_ws;
  ushort* xb   = (ushort*)(ws);
  ushort* Wcat = (ushort*)(ws + 16777216);
  ushort* Wob  = (ushort*)(ws + 18350080);
  ushort* qkv  = (ushort*)(ws + 18874368);
  ushort* obuf = (ushort*)(ws + 69206016);
  int* perm    = (int*)(ws + 85983232);
  int* gstart  = perm + Sc;
  int* gsz     = gstart + NI;
  int* items   = gsz + NI;
  int* nitems  = items + MAXITEMS;

  sort_kernel<<<dim3(1), dim3(256), 0, stream>>>(ids, perm, gstart, gsz, items, nitems);
  cvt_x_kernel<<<dim3(Mtot * Ec / 4 / 256), dim3(256), 0, stream>>>(x, perm, xb);
  cvt_w_kernel<<<dim3(2048 * 512 / 4 / 256), dim3(256), 0, stream>>>(Wq, Wk, Wv, Wo, Wcat, Wob);
  gemm_bt<1536, true><<<dim3(Mtot / 128 * 12), dim3(256), 0, stream>>>(
      xb, Wcat, bq, bk, bv, perm, qkv, (float*)nullptr);
  attn5_kernel<<<dim3(MAXITEMS, Bc * Hc), dim3(64), 0, stream>>>(qkv, gstart, gsz, items,
                                                                 nitems, obuf);
  gemm_bt<512, false><<<dim3(Mtot / 128 * 4), dim3(256), 0, stream>>>(
      obuf, Wob, bo, bo, bo, perm, (ushort*)nullptr, out);
}